// Round 20
// baseline (216.865 us; speedup 1.0000x reference)
//
#include <hip/hip_runtime.h>
#include <stdint.h>
#include <math.h>

typedef __attribute__((ext_vector_type(8))) short bf16x8;
typedef __attribute__((ext_vector_type(4))) float f32x4;

__device__ __forceinline__ ushort f2bf(float f) {      // RTNE, finite inputs
    uint32_t u = __float_as_uint(f);
    u += 0x7fffu + ((u >> 16) & 1u);
    return (ushort)(u >> 16);
}

// ---------------- Threefry-2x32 (JAX-exact, partitionable mode) ----------------
__device__ __forceinline__ uint32_t rotl32(uint32_t v, int r) {
    return (v << r) | (v >> (32 - r));
}

__device__ __forceinline__ void threefry(uint32_t k0, uint32_t k1,
                                         uint32_t c0, uint32_t c1,
                                         uint32_t& o0, uint32_t& o1) {
    uint32_t ks2 = k0 ^ k1 ^ 0x1BD11BDAu;
    uint32_t x0 = c0 + k0, x1 = c1 + k1;
    x0 += x1; x1 = rotl32(x1, 13); x1 ^= x0;
    x0 += x1; x1 = rotl32(x1, 15); x1 ^= x0;
    x0 += x1; x1 = rotl32(x1, 26); x1 ^= x0;
    x0 += x1; x1 = rotl32(x1,  6); x1 ^= x0;
    x0 += k1;  x1 += ks2 + 1u;
    x0 += x1; x1 = rotl32(x1, 17); x1 ^= x0;
    x0 += x1; x1 = rotl32(x1, 29); x1 ^= x0;
    x0 += x1; x1 = rotl32(x1, 16); x1 ^= x0;
    x0 += x1; x1 = rotl32(x1, 24); x1 ^= x0;
    x0 += ks2; x1 += k0 + 2u;
    x0 += x1; x1 = rotl32(x1, 13); x1 ^= x0;
    x0 += x1; x1 = rotl32(x1, 15); x1 ^= x0;
    x0 += x1; x1 = rotl32(x1, 26); x1 ^= x0;
    x0 += x1; x1 = rotl32(x1,  6); x1 ^= x0;
    x0 += k0;  x1 += k1 + 3u;
    x0 += x1; x1 = rotl32(x1, 17); x1 ^= x0;
    x0 += x1; x1 = rotl32(x1, 29); x1 ^= x0;
    x0 += x1; x1 = rotl32(x1, 16); x1 ^= x0;
    x0 += x1; x1 = rotl32(x1, 24); x1 ^= x0;
    x0 += k1;  x1 += ks2 + 4u;
    x0 += x1; x1 = rotl32(x1, 13); x1 ^= x0;
    x0 += x1; x1 = rotl32(x1, 15); x1 ^= x0;
    x0 += x1; x1 = rotl32(x1, 26); x1 ^= x0;
    x0 += x1; x1 = rotl32(x1,  6); x1 ^= x0;
    x0 += ks2; x1 += k0 + 5u;
    o0 = x0; o1 = x1;
}

__device__ __forceinline__ uint32_t rbits32(uint32_t k0, uint32_t k1, uint32_t idx) {
    uint32_t o0, o1;
    threefry(k0, k1, 0u, idx, o0, o1);
    return o0 ^ o1;
}

__device__ __forceinline__ float u01_from_bits(uint32_t bits) {
    return __uint_as_float((bits >> 9) | 0x3f800000u) - 1.0f;
}

__device__ float erfinv_xla(float x) {
    #pragma clang fp contract(off)
    float w = -log1pf(-x * x);
    float p;
    if (w < 5.0f) {
        w = w - 2.5f;
        p = 2.81022636e-08f;
        p = 3.43273939e-07f + p * w;
        p = -3.5233877e-06f + p * w;
        p = -4.39150654e-06f + p * w;
        p = 0.00021858087f + p * w;
        p = -0.00125372503f + p * w;
        p = -0.00417768164f + p * w;
        p = 0.246640727f + p * w;
        p = 1.50140941f + p * w;
    } else {
        w = sqrtf(w) - 3.0f;
        p = -0.000200214257f;
        p = 0.000100950558f + p * w;
        p = 0.00134934322f + p * w;
        p = -0.00367342844f + p * w;
        p = 0.00573950773f + p * w;
        p = -0.0076224613f + p * w;
        p = 0.00943887047f + p * w;
        p = 1.00167406f + p * w;
        p = 2.83297682f + p * w;
    }
    return p * x;
}

// ---------------- workspace layout (float offsets) ----------------
#define P_OFF      0           // 8192*12
#define NK_OFF     98304       // 4 u32 (16 f reserved)
#define W2GT_OFF   98320       // 64*296 bf16 = 9472 f
#define WFB_OFF    107792      // 512*3136 bf16 = 802816 f
#define WP1B_OFF   910608      // 512*512 bf16 = 131072 f
#define WP2B_OFF   1041680     // 128*512 bf16 = 32768 f
#define DATA_OFF   1074448
#define BATCH_FLOATS 19703056ull

// ---------------- merged prep kernel (param + all weight preps) ----------------
__global__ void prep_kernel(float* __restrict__ P, uint32_t* __restrict__ NK,
                            const float* __restrict__ W2, ushort* __restrict__ W2gT,
                            const float* __restrict__ Wf, ushort* __restrict__ WfB,
                            const float* __restrict__ Wp1, ushort* __restrict__ Wp1B,
                            const float* __restrict__ Wp2, ushort* __restrict__ Wp2B) {
    int b = blockIdx.x, t = threadIdx.x;
    if (b < 32) {
        #pragma clang fp contract(off)
        int gid = b * 256 + t;
        int v = gid >> 12;
        int i = gid & 4095;

        uint32_t kv0, kv1;
        threefry(0u, 42u, 0u, (uint32_t)v, kv0, kv1);

        uint32_t sk0[11], sk1[11];
        #pragma unroll
        for (int j = 0; j < 11; ++j) threefry(kv0, kv1, 0u, (uint32_t)j, sk0[j], sk1[j]);

        float u[10];
        #pragma unroll
        for (int j = 0; j < 10; ++j) u[j] = u01_from_bits(rbits32(sk0[j], sk1[j], (uint32_t)i));

        float crop = floorf(28.0f * (0.7f + 0.3f * u[0]));
        float top  = floorf((28.0f - crop) * u[1]);
        float left = floorf((28.0f - crop) * u[2]);
        float flip = (u[3] < 0.5f) ? 1.0f : 0.0f;
        float rot  = (u[4] < 0.8f) ? 1.0f : 0.0f;
        float rad  = ((20.0f * u[5] - 10.0f) * 3.14159274101257324f) / 180.0f;
        float cj   = (u[6] < 0.8f) ? 1.0f : 0.0f;
        float bb   = 0.2f * u[7] - 0.1f;
        float cc   = 0.8f + 0.4f * u[8];
        float na   = (u[9] < 0.5f) ? 1.0f : 0.0f;

        float* p = P + gid * 12;
        p[0] = crop; p[1] = top; p[2] = left; p[3] = flip; p[4] = rot;
        p[5] = rad;  p[6] = cj;  p[7] = bb;   p[8] = cc;   p[9] = na;
        p[10] = cosf(rad); p[11] = sinf(rad);

        if (i == 0) { NK[v * 2] = sk0[10]; NK[v * 2 + 1] = sk1[10]; }
    } else if (b < 106) {
        int idx = (b - 32) * 256 + t;
        if (idx < 64 * 296) {
            int oc = idx / 296, k = idx % 296;
            float v = 0.0f;
            if (k < 288) {
                int s = k >> 5, ic = k & 31;
                int ky = s / 3, kx = s % 3;
                v = W2[((oc * 32 + ic) * 3 + ky) * 3 + kx];
            }
            W2gT[idx] = f2bf(v);
        }
    } else if (b < 6378) {
        int idx = (b - 106) * 256 + t;
        if (idx < 512 * 3136) {
            int n = idx / 3136, kp = idx % 3136;
            int pos = kp >> 6, oc = kp & 63;
            WfB[idx] = f2bf(Wf[n * 3136 + oc * 49 + pos]);
        }
    } else if (b < 7402) {
        int idx = (b - 6378) * 256 + t;
        if (idx < 512 * 512) Wp1B[idx] = f2bf(Wp1[idx]);
    } else {
        int idx = (b - 7402) * 256 + t;
        if (idx < 128 * 512) Wp2B[idx] = f2bf(Wp2[idx]);
    }
}

// Block-per-image augment -> PADDED 30x30 BF16 output (row stride 30, zero border)
__global__ __launch_bounds__(256) void augment_kernel(const float* __restrict__ x,
                                                      const float* __restrict__ P,
                                                      const uint32_t* __restrict__ NK,
                                                      ushort* __restrict__ AUGB, int base) {
    #pragma clang fp contract(off)
    int li = blockIdx.x;
    int r = base + li;
    int v = r >> 12, i = r & 4095;
    int t = threadIdx.x;
    __shared__ float img[784];
    __shared__ float s1[784];
    __shared__ float srctab[28];

    const float* p = P + r * 12;
    float crop = p[0], top = p[1], left = p[2];
    int flip = (p[3] != 0.0f);
    int rot  = (p[4] != 0.0f);
    int cj = (p[6] != 0.0f);
    float bb = p[7], cc = p[8];
    int na = (p[9] != 0.0f);
    float cs = p[10], sn = p[11];
    uint32_t nk0 = NK[v * 2], nk1 = NK[v * 2 + 1];

    ushort* Ao = AUGB + (size_t)li * 900;
    for (int q = t; q < 450; q += 256) ((uint32_t*)Ao)[q] = 0u;

    for (int q = t; q < 784; q += 256) img[q] = x[i * 784 + q];
    if (t < 28) {
        float j = (float)t + 0.5f;
        float s = j * crop / 28.0f - 0.5f;
        srctab[t] = fminf(fmaxf(s, 0.0f), crop - 1.0f);
    }
    __syncthreads();

    for (int q = t; q < 784; q += 256) {
        int py = q / 28, px = q - (q / 28) * 28;
        int sxcol = flip ? (27 - px) : px;
        float yy = srctab[py] + top;
        float xx = srctab[sxcol] + left;
        float y0f = floorf(yy), x0f = floorf(xx);
        float wy = yy - y0f, wx = xx - x0f;
        int y0 = (int)y0f, x0 = (int)x0f;

        int yc0 = min(max(y0, 0), 27),     xc0 = min(max(x0, 0), 27);
        int yc1 = min(max(y0 + 1, 0), 27), xc1 = min(max(x0 + 1, 0), 27);
        float g00 = img[yc0 * 28 + xc0];
        float g01 = img[yc0 * 28 + xc1];
        float g10 = img[yc1 * 28 + xc0];
        float g11 = img[yc1 * 28 + xc1];
        float val = g00 * (1.0f - wy) * (1.0f - wx) + g01 * (1.0f - wy) * wx
                  + g10 * wy * (1.0f - wx) + g11 * wy * wx;
        s1[q] = val;
    }
    __syncthreads();

    for (int q = t; q < 784; q += 256) {
        int py = q / 28, px = q - (q / 28) * 28;
        float val;
        if (rot) {
            float Yn = (2.0f * (float)py + 1.0f) / 28.0f - 1.0f;
            float Xn = (2.0f * (float)px + 1.0f) / 28.0f - 1.0f;
            float xs = cs * Xn - sn * Yn;
            float ys = sn * Xn + cs * Yn;
            float ix = ((xs + 1.0f) * 28.0f - 1.0f) / 2.0f;
            float iy = ((ys + 1.0f) * 28.0f - 1.0f) / 2.0f;
            float y0f = floorf(iy), x0f = floorf(ix);
            float wy = iy - y0f, wx = ix - x0f;
            int y0 = (int)y0f, x0 = (int)x0f;
            float g[2][2];
            #pragma unroll
            for (int dy = 0; dy < 2; ++dy) {
                #pragma unroll
                for (int dx = 0; dx < 2; ++dx) {
                    int yi = y0 + dy, xi = x0 + dx;
                    int yc = min(max(yi, 0), 27), xc = min(max(xi, 0), 27);
                    float vv = s1[yc * 28 + xc];
                    float valid = (yi >= 0 && yi < 28 && xi >= 0 && xi < 28) ? 1.0f : 0.0f;
                    g[dy][dx] = vv * valid;
                }
            }
            val = g[0][0] * (1.0f - wy) * (1.0f - wx) + g[0][1] * (1.0f - wy) * wx
                + g[1][0] * wy * (1.0f - wx) + g[1][1] * wy * wx;
        } else {
            val = s1[q];
        }

        if (cj) {
            float vc = fminf(fmaxf(val + bb, 0.0f), 1.0f);
            val = fminf(fmaxf((vc - 0.5f) * cc + 0.5f, 0.0f), 1.0f);
        }

        if (na) {
            int idx = i * 784 + q;
            uint32_t bits = rbits32(nk0, nk1, (uint32_t)idx);
            float f = u01_from_bits(bits);
            const float lo = -0.99999994f;
            float uu = f * 2.0f + lo;
            uu = fmaxf(lo, uu);
            float n = 1.4142135623730951f * erfinv_xla(uu);
            val = fminf(fmaxf(val + 0.05f * n, 0.0f), 1.0f);
        }

        Ao[(py + 1) * 30 + (px + 1)] = f2bf((val - 0.5f) / 0.5f);
    }
}

// conv12: conv1 MFMA (bf16 padded im2col, XOR-swizzled A1) + conv2 MFMA
// (wave-per-oc-tile, ROLLING row reuse: 6 ds_reads per pyp instead of 12).
__global__ __launch_bounds__(256) void conv12_kernel(
        const ushort* __restrict__ AUGB,
        const float* __restrict__ W1, const float* __restrict__ b1,
        const ushort* __restrict__ W2gT, const float* __restrict__ b2,
        ushort* __restrict__ PL2) {
    int i = blockIdx.x, t = threadIdx.x;
    __shared__ __align__(16) ushort buf[12608];           // 1576 uint4 units
    __shared__ __align__(16) ushort w1sT[32 * 32];        // [oc][k]
    __shared__ ushort ptbl[196];                          // scatter bases
    ushort* A1   = buf;
    ushort* pl1p = buf;

    {
        int q0 = t * 4;
        #pragma unroll
        for (int j = 0; j < 4; ++j) {
            int q = q0 + j;
            int oc = q >> 5, k = q & 31;
            w1sT[q] = (k < 9) ? f2bf(W1[oc * 9 + k]) : (ushort)0;
        }
    }

    const ushort* Ai = AUGB + (size_t)i * 900;
    if (t < 196) {
        int py = t / 14, px = t - (t / 14) * 14;
        int e0 = (2 * py) * 30 + 2 * px;     // even -> u32-aligned
        uint32_t L[4], H[4];
        #pragma unroll
        for (int ry = 0; ry < 4; ++ry) {
            L[ry] = *(const uint32_t*)(Ai + e0 + ry * 30);       // c0|c1<<16
            H[ry] = *(const uint32_t*)(Ai + e0 + ry * 30 + 2);   // c2|c3<<16
        }
        int tx = t & 7;
        #pragma unroll
        for (int w = 0; w < 4; ++w) {
            int dy = w >> 1, dx = w & 1;
            uint32_t r0L = L[dy],     r0H = H[dy];
            uint32_t r1L = L[dy + 1], r1H = H[dy + 1];
            uint32_t r2L = L[dy + 2], r2H = H[dy + 2];
            uint4 W0, W1v;
            if (dx == 0) {
                W0.x = r0L;
                W0.y = (r0H & 0xffffu) | (r1L << 16);
                W0.z = (r1L >> 16) | (r1H << 16);
                W0.w = r2L;
                W1v.x = r2H & 0xffffu;
            } else {
                W0.x = (r0L >> 16) | (r0H << 16);
                W0.y = (r0H >> 16) | (r1L & 0xffff0000u);
                W0.z = r1H;
                W0.w = (r2L >> 16) | (r2H << 16);
                W1v.x = r2H >> 16;
            }
            W1v.y = 0; W1v.z = 0; W1v.w = 0;
            int u0 = t * 8 + w * 2;
            ((uint4*)A1)[u0 ^ tx]       = W0;
            ((uint4*)A1)[(u0 + 1) ^ tx] = W1v;
        }
    } else if (t < 204) {
        ((uint4*)A1)[1568 + (t - 196)] = uint4{0, 0, 0, 0};
    } else {
        for (int e = t - 204; e < 196; e += 52) {
            int py = e / 14, px = e - (e / 14) * 14;
            ptbl[e] = (ushort)(((py + 1) * 18 + (px + 1)) * 40);
        }
    }
    __syncthreads();

    int l = t & 63, wv = t >> 6;
    int lr = l & 15, lg = l >> 4;

    float m0r[13], m1r[13];
    {
        bf16x8 bA = *(const bf16x8*)(w1sT + lr * 32 + lg * 8);
        bf16x8 bB = *(const bf16x8*)(w1sT + (16 + lr) * 32 + lg * 8);
        #pragma unroll
        for (int it = 0; it < 13; ++it) {
            int tt = wv + it * 4;
            if (tt < 49) {
                int u = (tt * 16 + lr) * 2 + lg;
                int su = u ^ ((u >> 3) & 7);
                bf16x8 af = *(const bf16x8*)(A1 + su * 8);
                f32x4 a0 = {0.0f, 0.0f, 0.0f, 0.0f};
                f32x4 a1acc = {0.0f, 0.0f, 0.0f, 0.0f};
                a0    = __builtin_amdgcn_mfma_f32_16x16x32_bf16(af, bA, a0, 0, 0, 0);
                a1acc = __builtin_amdgcn_mfma_f32_16x16x32_bf16(af, bB, a1acc, 0, 0, 0);
                m0r[it] = fmaxf(fmaxf(a0[0], a0[1]), fmaxf(a0[2], a0[3]));
                m1r[it] = fmaxf(fmaxf(a1acc[0], a1acc[1]), fmaxf(a1acc[2], a1acc[3]));
            }
        }
    }
    __syncthreads();

    for (int q = t; q < 1440; q += 256) ((uint4*)pl1p)[q] = uint4{0, 0, 0, 0};
    __syncthreads();

    {
        float bia0 = b1[lr], bia1 = b1[16 + lr];
        #pragma unroll
        for (int it = 0; it < 13; ++it) {
            int tt = wv + it * 4;
            if (tt < 49) {
                int base = (int)ptbl[tt * 4 + lg];
                pl1p[base + lr]      = f2bf(fmaxf(m0r[it] + bia0, 0.0f));
                pl1p[base + 16 + lr] = f2bf(fmaxf(m1r[it] + bia1, 0.0f));
            }
        }
    }
    __syncthreads();

    {
        bf16x8 bfr[9];
        #pragma unroll
        for (int s = 0; s < 9; ++s)
            bfr[s] = *(const bf16x8*)(W2gT + (wv * 16 + lr) * 296 + s * 32 + lg * 8);
        float bias2 = b2[wv * 16 + lr];

        #define LDROW(dst, j) { \
            _Pragma("unroll") \
            for (int kx = 0; kx < 3; ++kx) \
                dst[kx] = *(const bf16x8*)(pl1p + (((j) * 18) + (lr + kx)) * 40 + lg * 8); }

        #define EMIT(pyp, R0, R1, R2, R3) { \
            f32x4 acc0 = {bias2, bias2, bias2, bias2}; \
            f32x4 acc1 = acc0; \
            _Pragma("unroll") \
            for (int kx = 0; kx < 3; ++kx) { \
                acc0 = __builtin_amdgcn_mfma_f32_16x16x32_bf16(R0[kx], bfr[kx], acc0, 0, 0, 0); \
                acc1 = __builtin_amdgcn_mfma_f32_16x16x32_bf16(R1[kx], bfr[kx], acc1, 0, 0, 0); } \
            _Pragma("unroll") \
            for (int kx = 0; kx < 3; ++kx) { \
                acc0 = __builtin_amdgcn_mfma_f32_16x16x32_bf16(R1[kx], bfr[3 + kx], acc0, 0, 0, 0); \
                acc1 = __builtin_amdgcn_mfma_f32_16x16x32_bf16(R2[kx], bfr[3 + kx], acc1, 0, 0, 0); } \
            _Pragma("unroll") \
            for (int kx = 0; kx < 3; ++kx) { \
                acc0 = __builtin_amdgcn_mfma_f32_16x16x32_bf16(R2[kx], bfr[6 + kx], acc0, 0, 0, 0); \
                acc1 = __builtin_amdgcn_mfma_f32_16x16x32_bf16(R3[kx], bfr[6 + kx], acc1, 0, 0, 0); } \
            float v0 = fmaxf(fmaxf(fmaxf(acc0[0], acc0[1]), fmaxf(acc1[0], acc1[1])), 0.0f); \
            float v1 = fmaxf(fmaxf(fmaxf(acc0[2], acc0[3]), fmaxf(acc1[2], acc1[3])), 0.0f); \
            int px0 = lg * 2, px1 = px0 + 1; \
            size_t obase = (size_t)i * 3136 + (size_t)((pyp) * 7) * 64 + wv * 16 + lr; \
            PL2[obase + (size_t)px0 * 64] = f2bf(v0); \
            if (px1 < 7) PL2[obase + (size_t)px1 * 64] = f2bf(v1); }

        // rolling 4-slot register file over pl1p rows (rows py0..py0+3 per pyp,
        // 2-row overlap between consecutive pyp -> only 2 new rows loaded each)
        bf16x8 A_[3], B_[3], C_[3], D_[3];
        LDROW(A_, 0) LDROW(B_, 1) LDROW(C_, 2) LDROW(D_, 3)
        EMIT(0, A_, B_, C_, D_)
        LDROW(A_, 4) LDROW(B_, 5)
        EMIT(1, C_, D_, A_, B_)
        LDROW(C_, 6) LDROW(D_, 7)
        EMIT(2, A_, B_, C_, D_)
        LDROW(A_, 8) LDROW(B_, 9)
        EMIT(3, C_, D_, A_, B_)
        LDROW(C_, 10) LDROW(D_, 11)
        EMIT(4, A_, B_, C_, D_)
        LDROW(A_, 12) LDROW(B_, 13)
        EMIT(5, C_, D_, A_, B_)
        LDROW(C_, 14) LDROW(D_, 15)
        EMIT(6, A_, B_, C_, D_)
        #undef LDROW
        #undef EMIT
    }
}

// Generic bf16 GEMM: C[M][N] = A[M][K] * BT[N][K]^T + bias, 64x64 tile, BK=64,
// 4 waves (2x2), double-buffered swizzled LDS (proven).
template<bool RELU, bool OUT_BF16>
__global__ __launch_bounds__(256) void gemm_bt_kernel(
        const ushort* __restrict__ A, const ushort* __restrict__ BT,
        const float* __restrict__ bias, void* __restrict__ Cout,
        int M, int N, int K) {
    __shared__ __align__(16) ushort lds[2][2][4096];   // [buf][A/B][64*64] bf16
    int t = threadIdx.x;
    int w = t >> 6, l = t & 63;
    int lr = l & 15, lc = l >> 4;
    int wm = w >> 1, wn = w & 1;
    int bm = blockIdx.x, bn = blockIdx.y;
    int NKt = K >> 6;

    const ushort* Ab = A + (size_t)bm * 64 * K;
    const ushort* Bb = BT + (size_t)bn * 64 * K;

    int r0 = t >> 3, s0 = t & 7;
    int c1i = t + 256;
    int r1 = c1i >> 3, s1 = c1i & 7;
    int d0 = r0 * 8 + (s0 ^ (r0 & 7));
    int d1 = r1 * 8 + (s1 ^ (r1 & 7));

    f32x4 acc[2][2] = {};

    uint4 tA0, tA1, tB0, tB1;
    #define GLOAD(kt) do { \
        tA0 = *(const uint4*)(Ab + (size_t)r0 * K + (kt) * 64 + s0 * 8); \
        tA1 = *(const uint4*)(Ab + (size_t)r1 * K + (kt) * 64 + s1 * 8); \
        tB0 = *(const uint4*)(Bb + (size_t)r0 * K + (kt) * 64 + s0 * 8); \
        tB1 = *(const uint4*)(Bb + (size_t)r1 * K + (kt) * 64 + s1 * 8); } while (0)
    #define LWRITE(bufi) do { \
        ((uint4*)lds[bufi][0])[d0] = tA0; ((uint4*)lds[bufi][0])[d1] = tA1; \
        ((uint4*)lds[bufi][1])[d0] = tB0; ((uint4*)lds[bufi][1])[d1] = tB1; } while (0)

    GLOAD(0); LWRITE(0);
    int buf = 0;
    for (int kt = 0; kt < NKt; ++kt) {
        __syncthreads();
        if (kt + 1 < NKt) GLOAD(kt + 1);
        const ushort* Al = lds[buf][0];
        const ushort* Bl = lds[buf][1];
        #pragma unroll
        for (int ks = 0; ks < 2; ++ks) {
            bf16x8 af[2], bg[2];
            #pragma unroll
            for (int mt = 0; mt < 2; ++mt) {
                int row = wm * 32 + mt * 16 + lr;
                int unit = row * 8 + ((ks * 4 + lc) ^ (row & 7));
                af[mt] = *(const bf16x8*)(Al + unit * 8);
            }
            #pragma unroll
            for (int nt = 0; nt < 2; ++nt) {
                int row = wn * 32 + nt * 16 + lr;
                int unit = row * 8 + ((ks * 4 + lc) ^ (row & 7));
                bg[nt] = *(const bf16x8*)(Bl + unit * 8);
            }
            #pragma unroll
            for (int mt = 0; mt < 2; ++mt)
                #pragma unroll
                for (int nt = 0; nt < 2; ++nt)
                    acc[mt][nt] = __builtin_amdgcn_mfma_f32_16x16x32_bf16(af[mt], bg[nt], acc[mt][nt], 0, 0, 0);
        }
        if (kt + 1 < NKt) LWRITE(buf ^ 1);
        buf ^= 1;
    }

    #pragma unroll
    for (int nt = 0; nt < 2; ++nt) {
        int gcol = bn * 64 + wn * 32 + nt * 16 + lr;
        float bv = bias[gcol];
        #pragma unroll
        for (int mt = 0; mt < 2; ++mt) {
            #pragma unroll
            for (int rg = 0; rg < 4; ++rg) {
                int grow = bm * 64 + wm * 32 + mt * 16 + lc * 4 + rg;
                float vv = acc[mt][nt][rg] + bv;
                if (RELU) vv = fmaxf(vv, 0.0f);
                if (OUT_BF16) ((ushort*)Cout)[(size_t)grow * N + gcol] = f2bf(vv);
                else          ((float*)Cout)[(size_t)grow * N + gcol] = vv;
            }
        }
    }
    #undef GLOAD
    #undef LWRITE
}

// ---------------- launch ----------------
extern "C" void kernel_launch(void* const* d_in, const int* in_sizes, int n_in,
                              void* d_out, int out_size, void* d_ws, size_t ws_size,
                              hipStream_t stream) {
    const float* x   = (const float*)d_in[0];
    const float* W1  = (const float*)d_in[1];
    const float* b1  = (const float*)d_in[2];
    const float* W2  = (const float*)d_in[3];
    const float* b2  = (const float*)d_in[4];
    const float* Wf  = (const float*)d_in[5];
    const float* bf  = (const float*)d_in[6];
    const float* Wp1 = (const float*)d_in[7];
    const float* bp1 = (const float*)d_in[8];
    const float* Wp2 = (const float*)d_in[9];
    const float* bp2 = (const float*)d_in[10];

    float* ws     = (float*)d_ws;
    float* P      = ws + P_OFF;
    uint32_t* NK  = (uint32_t*)(ws + NK_OFF);
    ushort* W2gT  = (ushort*)(ws + W2GT_OFF);
    ushort* WfB   = (ushort*)(ws + WFB_OFF);
    ushort* Wp1B  = (ushort*)(ws + WP1B_OFF);
    ushort* Wp2B  = (ushort*)(ws + WP2B_OFF);
    float* out    = (float*)d_out;

    prep_kernel<<<7658, 256, 0, stream>>>(P, NK, W2, W2gT, Wf, WfB,
                                          Wp1, Wp1B, Wp2, Wp2B);

    if (ws_size >= BATCH_FLOATS * 4ull) {
        // -------- batched: both views, padded bf16 AUG -----------------------
        ushort* AUGB8 = (ushort*)(ws + DATA_OFF);            // 8192*900 bf16
        ushort* PL28  = (ushort*)(ws + DATA_OFF + 3686400);  // 8192*3136 bf16
        ushort* H8    = (ushort*)(ws + DATA_OFF + 16531456); // 8192*512 bf16
        ushort* P18   = AUGB8;                               // alias

        augment_kernel<<<8192, 256, 0, stream>>>(x, P, NK, AUGB8, 0);
        conv12_kernel<<<8192, 256, 0, stream>>>(AUGB8, W1, b1, W2gT, b2, PL28);
        gemm_bt_kernel<false, true><<<dim3(128, 8), 256, 0, stream>>>(
            PL28, WfB, bf, H8, 8192, 512, 3136);
        gemm_bt_kernel<true, true><<<dim3(128, 8), 256, 0, stream>>>(
            H8, Wp1B, bp1, P18, 8192, 512, 512);
        gemm_bt_kernel<false, false><<<dim3(128, 2), 256, 0, stream>>>(
            P18, Wp2B, bp2, out, 8192, 128, 512);
    } else {
        // -------- per-view fallback (padded bf16 AUG) ------------------------
        ushort* AUGB = (ushort*)(ws + DATA_OFF);             // 4096*900 bf16
        ushort* PL2  = (ushort*)(ws + DATA_OFF + 1843200);   // 4096*3136 bf16
        ushort* Hb   = (ushort*)(ws + DATA_OFF + 8265728);   // 4096*512 bf16
        ushort* P1   = AUGB;

        for (int v = 0; v < 2; ++v) {
            augment_kernel<<<4096, 256, 0, stream>>>(x, P, NK, AUGB, v * 4096);
            conv12_kernel<<<4096, 256, 0, stream>>>(AUGB, W1, b1, W2gT, b2, PL2);
            gemm_bt_kernel<false, true><<<dim3(64, 8), 256, 0, stream>>>(
                PL2, WfB, bf, Hb, 4096, 512, 3136);
            gemm_bt_kernel<true, true><<<dim3(64, 8), 256, 0, stream>>>(
                Hb, Wp1B, bp1, P1, 4096, 512, 512);
            gemm_bt_kernel<false, false><<<dim3(64, 2), 256, 0, stream>>>(
                P1, Wp2B, bp2, out + (size_t)v * 4096 * 128, 4096, 128, 512);
        }
    }
}